// Round 1
// baseline (1375.784 us; speedup 1.0000x reference)
//
#include <hip/hip_runtime.h>

#define BS 256

// ---- order-preserving float<->uint encoding for atomicMax on signed floats ----
__device__ __forceinline__ unsigned fenc(float f) {
    unsigned u = __float_as_uint(f);
    return (u & 0x80000000u) ? ~u : (u | 0x80000000u);
}
__device__ __forceinline__ float fdec(unsigned v) {
    unsigned u = (v & 0x80000000u) ? (v ^ 0x80000000u) : ~v;
    return __uint_as_float(u);
}
#define ENC_NEG_INF 0x007FFFFFu  // fenc(-inf)

// ---- node prep: x16 = relu(relu(x_feat @ lpW + lpb) @ tW + tb) ----
__global__ void prep_kernel(const float* __restrict__ xf,
                            const float* __restrict__ W1, const float* __restrict__ b1,
                            const float* __restrict__ W2, const float* __restrict__ b2,
                            float* __restrict__ x16, int N)
{
    int n = blockIdx.x * blockDim.x + threadIdx.x;
    bool valid = n < N;
    int nn = valid ? n : 0;
    float a[24];
#pragma unroll
    for (int i = 0; i < 24; i += 4)
        *(float4*)(a + i) = *(const float4*)(xf + (size_t)nn * 24 + i);
    float h[32];
#pragma unroll
    for (int j = 0; j < 32; j++) {
        float s = b1[j];
#pragma unroll
        for (int i = 0; i < 24; i++) s = fmaf(a[i], W1[i * 32 + j], s);
        h[j] = fmaxf(s, 0.f);
    }
    if (!valid) return;
#pragma unroll
    for (int j = 0; j < 16; j++) {
        float s = b2[j];
#pragma unroll
        for (int i = 0; i < 32; i++) s = fmaf(h[i], W2[i * 16 + j], s);
        x16[(size_t)n * 16 + j] = fmaxf(s, 0.f);
    }
}

// ---- init aggregation buffers (and deg on first call) ----
__global__ void init_kernel(float* __restrict__ sum_mean, unsigned* __restrict__ maxenc,
                            float* __restrict__ sum_add, float* __restrict__ deg,
                            int n8, int ndeg)
{
    int i = blockIdx.x * blockDim.x + threadIdx.x;
    if (i < n8) { sum_mean[i] = 0.f; maxenc[i] = ENC_NEG_INF; sum_add[i] = 0.f; }
    if (i < ndeg) deg[i] = 0.f;
}

// ---- degree count ----
__global__ void deg_kernel(const int* __restrict__ dst, float* __restrict__ deg, int E)
{
    int i = blockIdx.x * blockDim.x + threadIdx.x;
    if (i < E) atomicAdd(&deg[dst[i]], 1.f);
}

// ---- per-edge: trunk MLP -> e_repr; messages for 3 aggregators; atomics to node bufs ----
template <int IN>
__global__ __launch_bounds__(BS) void conv_edge_kernel(
    const int* __restrict__ src, const int* __restrict__ dst,
    const float* __restrict__ eattr,
    const float* __restrict__ eW1, const float* __restrict__ eb1,
    const float* __restrict__ eW2, const float* __restrict__ eb2,
    const float* __restrict__ x,
    const float* __restrict__ W,   // [3][16][IN*8]
    const float* __restrict__ B,   // [3][IN*8]
    float* __restrict__ sum_mean, unsigned* __restrict__ maxenc,
    float* __restrict__ sum_add, int E)
{
    __shared__ float er_lds[16 * BS];
    int t = threadIdx.x;
    int e = blockIdx.x * BS + t;
    bool valid = e < E;
    int ee = valid ? e : 0;

    // ---- edge trunk (recomputed per conv; keeps ws small) ----
    float ea[16];
#pragma unroll
    for (int i = 0; i < 16; i += 4)
        *(float4*)(ea + i) = *(const float4*)(eattr + (size_t)ee * 16 + i);
    float h[32];
#pragma unroll
    for (int j = 0; j < 32; j++) {
        float s = eb1[j];
#pragma unroll
        for (int i = 0; i < 16; i++) s = fmaf(ea[i], eW1[i * 32 + j], s);
        h[j] = fmaxf(s, 0.f);
    }
#pragma unroll
    for (int j = 0; j < 16; j++) {
        float s = eb2[j];
#pragma unroll
        for (int i = 0; i < 32; i++) s = fmaf(h[i], eW2[i * 16 + j], s);
        er_lds[j * BS + t] = 1.f / (1.f + __expf(-s));  // sigmoid
    }

    // ---- gather source-node features ----
    float xv[IN];
    {
        const float* xs = x + (size_t)src[ee] * IN;
#pragma unroll
        for (int i = 0; i < IN; i += 4)
            *(float4*)(xv + i) = *(const float4*)(xs + i);
    }

    // ---- messages: msg[a,o] = sum_k er[k] * sum_i x[i]*W[a,k,i,o] + sum_i x[i]*B[a,i,o] ----
    float acc0[8], acc1[8], acc2[8];
#pragma unroll
    for (int o = 0; o < 8; o++) { acc0[o] = 0.f; acc1[o] = 0.f; acc2[o] = 0.f; }

    for (int k = 0; k < 16; k++) {               // rolled: er from LDS (runtime k)
        float ek = er_lds[k * BS + t];
        const float* w0 = W + (size_t)k * (IN * 8);
        const float* w1 = W + (size_t)(16 + k) * (IN * 8);
        const float* w2 = W + (size_t)(32 + k) * (IN * 8);
#pragma unroll
        for (int i = 0; i < IN; i++) {
            float p = ek * xv[i];
#pragma unroll
            for (int o = 0; o < 8; o++) {
                acc0[o] = fmaf(p, w0[i * 8 + o], acc0[o]);
                acc1[o] = fmaf(p, w1[i * 8 + o], acc1[o]);
                acc2[o] = fmaf(p, w2[i * 8 + o], acc2[o]);
            }
        }
    }
    // bias rows of W_e: + sum_i x[i] * B[a,i,o]
#pragma unroll
    for (int i = 0; i < IN; i++) {
        float xi = xv[i];
#pragma unroll
        for (int o = 0; o < 8; o++) {
            acc0[o] = fmaf(xi, B[i * 8 + o], acc0[o]);
            acc1[o] = fmaf(xi, B[IN * 8 + i * 8 + o], acc1[o]);
            acc2[o] = fmaf(xi, B[2 * IN * 8 + i * 8 + o], acc2[o]);
        }
    }

    // ---- scatter with atomics ----
    if (valid) {
        int d = dst[e];
        float* sm = sum_mean + (size_t)d * 8;
        unsigned* mx = maxenc + (size_t)d * 8;
        float* sa = sum_add + (size_t)d * 8;
#pragma unroll
        for (int o = 0; o < 8; o++) atomicAdd(sm + o, acc0[o]);
#pragma unroll
        for (int o = 0; o < 8; o++) atomicMax(mx + o, fenc(acc1[o]));
#pragma unroll
        for (int o = 0; o < 8; o++) atomicAdd(sa + o, acc2[o]);
    }
}

// ---- per-node finalize: aggr + x @ rootW + bias, relu ----
template <int IN>
__global__ void conv_node_kernel(const float* __restrict__ x,
                                 const float* __restrict__ sum_mean,
                                 const unsigned* __restrict__ maxenc,
                                 const float* __restrict__ sum_add,
                                 const float* __restrict__ deg,
                                 const float* __restrict__ rootW,  // [3][IN][8]
                                 const float* __restrict__ bias,   // [3][8]
                                 float* __restrict__ out, int N)
{
    int n = blockIdx.x * blockDim.x + threadIdx.x;
    bool valid = n < N;
    int nn = valid ? n : 0;
    float xv[IN];
#pragma unroll
    for (int i = 0; i < IN; i += 4)
        *(float4*)(xv + i) = *(const float4*)(x + (size_t)nn * IN + i);
    float d = deg[nn];
    float inv = 1.f / fmaxf(d, 1.f);
    float r[24];
#pragma unroll
    for (int a = 0; a < 3; a++) {
#pragma unroll
        for (int o = 0; o < 8; o++) {
            float s = bias[a * 8 + o];
#pragma unroll
            for (int i = 0; i < IN; i++) s = fmaf(xv[i], rootW[(a * IN + i) * 8 + o], s);
            r[a * 8 + o] = s;
        }
    }
    if (!valid) return;
#pragma unroll
    for (int o = 0; o < 8; o++) {
        float vmean = sum_mean[(size_t)n * 8 + o] * inv;
        float vmax = (d > 0.f) ? fdec(maxenc[(size_t)n * 8 + o]) : 0.f;
        float vadd = sum_add[(size_t)n * 8 + o];
        r[o] += vmean;
        r[8 + o] += vmax;
        r[16 + o] += vadd;
    }
#pragma unroll
    for (int j = 0; j < 24; j++)
        out[(size_t)n * 24 + j] = fmaxf(r[j], 0.f);
}

// ---- output head: logits + 2-class softmax ----
__global__ void head_kernel(const float* __restrict__ x, const float* __restrict__ W,
                            const float* __restrict__ b, float* __restrict__ out, int N)
{
    int n = blockIdx.x * blockDim.x + threadIdx.x;
    if (n >= N) return;
    float l0 = b[0], l1 = b[1];
#pragma unroll
    for (int i = 0; i < 24; i++) {
        float xi = x[(size_t)n * 24 + i];
        l0 = fmaf(xi, W[i * 2 + 0], l0);
        l1 = fmaf(xi, W[i * 2 + 1], l1);
    }
    out[2 * (size_t)n + 0] = l0;
    out[2 * (size_t)n + 1] = l1;
    float m = fmaxf(l0, l1);
    float e0 = __expf(l0 - m), e1 = __expf(l1 - m);
    float s = e0 + e1;
    out[2 * (size_t)N + 2 * (size_t)n + 0] = e0 / s;
    out[2 * (size_t)N + 2 * (size_t)n + 1] = e1 / s;
}

extern "C" void kernel_launch(void* const* d_in, const int* in_sizes, int n_in,
                              void* d_out, int out_size, void* d_ws, size_t ws_size,
                              hipStream_t stream)
{
    const float* x_feat = (const float*)d_in[0];
    const int*   eidx   = (const int*)d_in[1];
    const float* eattr  = (const float*)d_in[2];
    const float* lpW = (const float*)d_in[3];
    const float* lpb = (const float*)d_in[4];
    const float* tW  = (const float*)d_in[5];
    const float* tb  = (const float*)d_in[6];
    const float* eW1 = (const float*)d_in[7];
    const float* eb1 = (const float*)d_in[8];
    const float* eW2 = (const float*)d_in[9];
    const float* eb2 = (const float*)d_in[10];
    const float* c1W = (const float*)d_in[11];
    const float* c1B = (const float*)d_in[12];
    const float* c1R = (const float*)d_in[13];
    const float* c1b = (const float*)d_in[14];
    const float* c2W = (const float*)d_in[15];
    const float* c2B = (const float*)d_in[16];
    const float* c2R = (const float*)d_in[17];
    const float* c2b = (const float*)d_in[18];
    const float* oW  = (const float*)d_in[19];
    const float* ob  = (const float*)d_in[20];

    int N = in_sizes[0] / 24;
    int E = in_sizes[1] / 2;
    const int* src = eidx;
    const int* dstI = eidx + E;

    float* ws = (float*)d_ws;
    float* x16 = ws;                   ws += (size_t)N * 16;
    float* x24a = ws;                  ws += (size_t)N * 24;
    float* x24b = ws;                  ws += (size_t)N * 24;
    float* deg = ws;                   ws += N;
    float* sum_mean = ws;              ws += (size_t)N * 8;
    unsigned* maxenc = (unsigned*)ws;  ws += (size_t)N * 8;
    float* sum_add = ws;               ws += (size_t)N * 8;

    dim3 blk(BS);
    int nb_nodes = (N + BS - 1) / BS;
    int nb_edges = (E + BS - 1) / BS;
    int nb_n8 = (N * 8 + BS - 1) / BS;

    prep_kernel<<<nb_nodes, blk, 0, stream>>>(x_feat, lpW, lpb, tW, tb, x16, N);
    init_kernel<<<nb_n8, blk, 0, stream>>>(sum_mean, maxenc, sum_add, deg, N * 8, N);
    deg_kernel<<<nb_edges, blk, 0, stream>>>(dstI, deg, E);

    conv_edge_kernel<16><<<nb_edges, blk, 0, stream>>>(
        src, dstI, eattr, eW1, eb1, eW2, eb2, x16, c1W, c1B,
        sum_mean, maxenc, sum_add, E);
    conv_node_kernel<16><<<nb_nodes, blk, 0, stream>>>(
        x16, sum_mean, maxenc, sum_add, deg, c1R, c1b, x24a, N);

    init_kernel<<<nb_n8, blk, 0, stream>>>(sum_mean, maxenc, sum_add, nullptr, N * 8, 0);

    conv_edge_kernel<24><<<nb_edges, blk, 0, stream>>>(
        src, dstI, eattr, eW1, eb1, eW2, eb2, x24a, c2W, c2B,
        sum_mean, maxenc, sum_add, E);
    conv_node_kernel<24><<<nb_nodes, blk, 0, stream>>>(
        x24a, sum_mean, maxenc, sum_add, deg, c2R, c2b, x24b, N);

    head_kernel<<<nb_nodes, blk, 0, stream>>>(x24b, oW, ob, (float*)d_out, N);
}

// Round 2
// 368.532 us; speedup vs baseline: 3.7331x; 3.7331x over previous
//
#include <hip/hip_runtime.h>

#define BS 256

// ---- node prep: x16 = relu(relu(x_feat @ lpW + lpb) @ tW + tb) ----
__global__ void prep_kernel(const float* __restrict__ xf,
                            const float* __restrict__ W1, const float* __restrict__ b1,
                            const float* __restrict__ W2, const float* __restrict__ b2,
                            float* __restrict__ x16, int N)
{
    int n = blockIdx.x * blockDim.x + threadIdx.x;
    bool valid = n < N;
    int nn = valid ? n : 0;
    float a[24];
#pragma unroll
    for (int i = 0; i < 24; i += 4)
        *(float4*)(a + i) = *(const float4*)(xf + (size_t)nn * 24 + i);
    float h[32];
#pragma unroll
    for (int j = 0; j < 32; j++) {
        float s = b1[j];
#pragma unroll
        for (int i = 0; i < 24; i++) s = fmaf(a[i], W1[i * 32 + j], s);
        h[j] = fmaxf(s, 0.f);
    }
    if (!valid) return;
#pragma unroll
    for (int j = 0; j < 16; j++) {
        float s = b2[j];
#pragma unroll
        for (int i = 0; i < 32; i++) s = fmaf(h[i], W2[i * 16 + j], s);
        x16[(size_t)n * 16 + j] = fmaxf(s, 0.f);
    }
}

// ---- CSR build: degree count (int atomics) ----
__global__ void deg_kernel(const int* __restrict__ dst, int* __restrict__ degi, int E)
{
    int i = blockIdx.x * blockDim.x + threadIdx.x;
    if (i < E) atomicAdd(&degi[dst[i]], 1);
}

// ---- CSR build: grab contiguous range per node (order across nodes irrelevant) ----
__global__ void offsets_kernel(const int* __restrict__ degi, int* __restrict__ offs,
                               int* __restrict__ cur, int* __restrict__ cursor, int N)
{
    int n = blockIdx.x * blockDim.x + threadIdx.x;
    if (n < N) {
        int d = degi[n];
        int o = atomicAdd(cursor, d);
        offs[n] = o;
        cur[n] = o;
    }
}

// ---- CSR build: scatter edge ids into per-dst ranges ----
__global__ void fill_kernel(const int* __restrict__ dst, int* __restrict__ cur,
                            int* __restrict__ eid, int E)
{
    int e = blockIdx.x * blockDim.x + threadIdx.x;
    if (e < E) {
        int p = atomicAdd(&cur[dst[e]], 1);
        eid[p] = e;
    }
}

// ---- per-edge: trunk MLP -> e_repr; 3x8 messages; dense coalesced store ----
template <int IN>
__global__ __launch_bounds__(BS) void edge_msg_kernel(
    const int* __restrict__ src,
    const float* __restrict__ eattr,
    const float* __restrict__ eW1, const float* __restrict__ eb1,
    const float* __restrict__ eW2, const float* __restrict__ eb2,
    const float* __restrict__ x,
    const float* __restrict__ W,   // [3][16][IN*8]
    const float* __restrict__ B,   // [3][IN*8]
    float* __restrict__ msg,       // [E][24]
    int E)
{
    __shared__ float er_lds[16 * BS];
    int t = threadIdx.x;
    int e = blockIdx.x * BS + t;
    bool valid = e < E;
    int ee = valid ? e : 0;

    // ---- edge trunk ----
    float ea[16];
#pragma unroll
    for (int i = 0; i < 16; i += 4)
        *(float4*)(ea + i) = *(const float4*)(eattr + (size_t)ee * 16 + i);
    float h[32];
#pragma unroll
    for (int j = 0; j < 32; j++) {
        float s = eb1[j];
#pragma unroll
        for (int i = 0; i < 16; i++) s = fmaf(ea[i], eW1[i * 32 + j], s);
        h[j] = fmaxf(s, 0.f);
    }
#pragma unroll
    for (int j = 0; j < 16; j++) {
        float s = eb2[j];
#pragma unroll
        for (int i = 0; i < 32; i++) s = fmaf(h[i], eW2[i * 16 + j], s);
        er_lds[j * BS + t] = 1.f / (1.f + __expf(-s));  // sigmoid
    }

    // ---- gather source-node features ----
    float xv[IN];
    {
        const float* xs = x + (size_t)src[ee] * IN;
#pragma unroll
        for (int i = 0; i < IN; i += 4)
            *(float4*)(xv + i) = *(const float4*)(xs + i);
    }

    // ---- messages: msg[a,o] = sum_k er[k] * sum_i x[i]*W[a,k,i,o] + sum_i x[i]*B[a,i,o] ----
    float acc0[8], acc1[8], acc2[8];
#pragma unroll
    for (int o = 0; o < 8; o++) { acc0[o] = 0.f; acc1[o] = 0.f; acc2[o] = 0.f; }

    for (int k = 0; k < 16; k++) {               // rolled: er from LDS (runtime k)
        float ek = er_lds[k * BS + t];
        const float* w0 = W + (size_t)k * (IN * 8);
        const float* w1 = W + (size_t)(16 + k) * (IN * 8);
        const float* w2 = W + (size_t)(32 + k) * (IN * 8);
#pragma unroll
        for (int i = 0; i < IN; i++) {
            float p = ek * xv[i];
#pragma unroll
            for (int o = 0; o < 8; o++) {
                acc0[o] = fmaf(p, w0[i * 8 + o], acc0[o]);
                acc1[o] = fmaf(p, w1[i * 8 + o], acc1[o]);
                acc2[o] = fmaf(p, w2[i * 8 + o], acc2[o]);
            }
        }
    }
    // bias rows of W_e: + sum_i x[i] * B[a,i,o]
#pragma unroll
    for (int i = 0; i < IN; i++) {
        float xi = xv[i];
#pragma unroll
        for (int o = 0; o < 8; o++) {
            acc0[o] = fmaf(xi, B[i * 8 + o], acc0[o]);
            acc1[o] = fmaf(xi, B[IN * 8 + i * 8 + o], acc1[o]);
            acc2[o] = fmaf(xi, B[2 * IN * 8 + i * 8 + o], acc2[o]);
        }
    }

    // ---- coalesced dense store (no atomics) ----
    if (valid) {
        float* m = msg + (size_t)e * 24;
        *(float4*)(m + 0)  = make_float4(acc0[0], acc0[1], acc0[2], acc0[3]);
        *(float4*)(m + 4)  = make_float4(acc0[4], acc0[5], acc0[6], acc0[7]);
        *(float4*)(m + 8)  = make_float4(acc1[0], acc1[1], acc1[2], acc1[3]);
        *(float4*)(m + 12) = make_float4(acc1[4], acc1[5], acc1[6], acc1[7]);
        *(float4*)(m + 16) = make_float4(acc2[0], acc2[1], acc2[2], acc2[3]);
        *(float4*)(m + 20) = make_float4(acc2[4], acc2[5], acc2[6], acc2[7]);
    }
}

// ---- per-node gather + root transform + relu (no atomics) ----
template <int IN>
__global__ void gather_kernel(const float* __restrict__ x,
                              const float* __restrict__ msg,   // [E][24]
                              const int* __restrict__ offs,
                              const int* __restrict__ degi,
                              const int* __restrict__ eid,
                              const float* __restrict__ rootW, // [3][IN][8]
                              const float* __restrict__ bias,  // [3][8]
                              float* __restrict__ out, int N)
{
    int n = blockIdx.x * blockDim.x + threadIdx.x;
    if (n >= N) return;

    float am[8], ax[8], aa[8];
#pragma unroll
    for (int o = 0; o < 8; o++) { am[o] = 0.f; aa[o] = 0.f; ax[o] = -3.402823466e38f; }

    int off = offs[n];
    int d = degi[n];
    for (int j = 0; j < d; j++) {
        int e = eid[off + j];
        const float* m = msg + (size_t)e * 24;
        float4 m0 = *(const float4*)(m + 0);
        float4 m1 = *(const float4*)(m + 4);
        float4 m2 = *(const float4*)(m + 8);
        float4 m3 = *(const float4*)(m + 12);
        float4 m4 = *(const float4*)(m + 16);
        float4 m5 = *(const float4*)(m + 20);
        am[0] += m0.x; am[1] += m0.y; am[2] += m0.z; am[3] += m0.w;
        am[4] += m1.x; am[5] += m1.y; am[6] += m1.z; am[7] += m1.w;
        ax[0] = fmaxf(ax[0], m2.x); ax[1] = fmaxf(ax[1], m2.y);
        ax[2] = fmaxf(ax[2], m2.z); ax[3] = fmaxf(ax[3], m2.w);
        ax[4] = fmaxf(ax[4], m3.x); ax[5] = fmaxf(ax[5], m3.y);
        ax[6] = fmaxf(ax[6], m3.z); ax[7] = fmaxf(ax[7], m3.w);
        aa[0] += m4.x; aa[1] += m4.y; aa[2] += m4.z; aa[3] += m4.w;
        aa[4] += m5.x; aa[5] += m5.y; aa[6] += m5.z; aa[7] += m5.w;
    }

    float xv[IN];
#pragma unroll
    for (int i = 0; i < IN; i += 4)
        *(float4*)(xv + i) = *(const float4*)(x + (size_t)n * IN + i);

    float inv = 1.f / fmaxf((float)d, 1.f);
    float r[24];
#pragma unroll
    for (int a = 0; a < 3; a++) {
#pragma unroll
        for (int o = 0; o < 8; o++) {
            float s = bias[a * 8 + o];
#pragma unroll
            for (int i = 0; i < IN; i++) s = fmaf(xv[i], rootW[(a * IN + i) * 8 + o], s);
            r[a * 8 + o] = s;
        }
    }
#pragma unroll
    for (int o = 0; o < 8; o++) {
        r[o]      += am[o] * inv;
        r[8 + o]  += (d > 0) ? ax[o] : 0.f;
        r[16 + o] += aa[o];
    }
#pragma unroll
    for (int j = 0; j < 24; j++)
        out[(size_t)n * 24 + j] = fmaxf(r[j], 0.f);
}

// ---- output head: logits + 2-class softmax ----
__global__ void head_kernel(const float* __restrict__ x, const float* __restrict__ W,
                            const float* __restrict__ b, float* __restrict__ out, int N)
{
    int n = blockIdx.x * blockDim.x + threadIdx.x;
    if (n >= N) return;
    float l0 = b[0], l1 = b[1];
#pragma unroll
    for (int i = 0; i < 24; i++) {
        float xi = x[(size_t)n * 24 + i];
        l0 = fmaf(xi, W[i * 2 + 0], l0);
        l1 = fmaf(xi, W[i * 2 + 1], l1);
    }
    out[2 * (size_t)n + 0] = l0;
    out[2 * (size_t)n + 1] = l1;
    float m = fmaxf(l0, l1);
    float e0 = __expf(l0 - m), e1 = __expf(l1 - m);
    float s = e0 + e1;
    out[2 * (size_t)N + 2 * (size_t)n + 0] = e0 / s;
    out[2 * (size_t)N + 2 * (size_t)n + 1] = e1 / s;
}

extern "C" void kernel_launch(void* const* d_in, const int* in_sizes, int n_in,
                              void* d_out, int out_size, void* d_ws, size_t ws_size,
                              hipStream_t stream)
{
    const float* x_feat = (const float*)d_in[0];
    const int*   eidx   = (const int*)d_in[1];
    const float* eattr  = (const float*)d_in[2];
    const float* lpW = (const float*)d_in[3];
    const float* lpb = (const float*)d_in[4];
    const float* tW  = (const float*)d_in[5];
    const float* tb  = (const float*)d_in[6];
    const float* eW1 = (const float*)d_in[7];
    const float* eb1 = (const float*)d_in[8];
    const float* eW2 = (const float*)d_in[9];
    const float* eb2 = (const float*)d_in[10];
    const float* c1W = (const float*)d_in[11];
    const float* c1B = (const float*)d_in[12];
    const float* c1R = (const float*)d_in[13];
    const float* c1b = (const float*)d_in[14];
    const float* c2W = (const float*)d_in[15];
    const float* c2B = (const float*)d_in[16];
    const float* c2R = (const float*)d_in[17];
    const float* c2b = (const float*)d_in[18];
    const float* oW  = (const float*)d_in[19];
    const float* ob  = (const float*)d_in[20];

    int N = in_sizes[0] / 24;
    int E = in_sizes[1] / 2;
    const int* src = eidx;
    const int* dstI = eidx + E;

    // ---- workspace layout (msg first: 16B alignment for float4 rows) ----
    char* wsb = (char*)d_ws;
    float* msg  = (float*)wsb;                wsb += (size_t)E * 24 * sizeof(float);
    float* x16  = (float*)wsb;                wsb += (size_t)N * 16 * sizeof(float);
    float* x24a = (float*)wsb;                wsb += (size_t)N * 24 * sizeof(float);
    float* x24b = (float*)wsb;                wsb += (size_t)N * 24 * sizeof(float);
    int* degi   = (int*)wsb;                  wsb += (size_t)N * sizeof(int);
    int* cursor = (int*)wsb;                  wsb += sizeof(int);
    int* offs   = (int*)wsb;                  wsb += (size_t)N * sizeof(int);
    int* cur    = (int*)wsb;                  wsb += (size_t)N * sizeof(int);
    int* eid    = (int*)wsb;                  wsb += (size_t)E * sizeof(int);

    dim3 blk(BS);
    int nb_nodes = (N + BS - 1) / BS;
    int nb_edges = (E + BS - 1) / BS;

    // zero degree counters + cursor (contiguous)
    hipMemsetAsync(degi, 0, (N + 1) * sizeof(int), stream);

    prep_kernel<<<nb_nodes, blk, 0, stream>>>(x_feat, lpW, lpb, tW, tb, x16, N);
    deg_kernel<<<nb_edges, blk, 0, stream>>>(dstI, degi, E);
    offsets_kernel<<<nb_nodes, blk, 0, stream>>>(degi, offs, cur, cursor, N);
    fill_kernel<<<nb_edges, blk, 0, stream>>>(dstI, cur, eid, E);

    edge_msg_kernel<16><<<nb_edges, blk, 0, stream>>>(
        src, eattr, eW1, eb1, eW2, eb2, x16, c1W, c1B, msg, E);
    gather_kernel<16><<<nb_nodes, blk, 0, stream>>>(
        x16, msg, offs, degi, eid, c1R, c1b, x24a, N);

    edge_msg_kernel<24><<<nb_edges, blk, 0, stream>>>(
        src, eattr, eW1, eb1, eW2, eb2, x24a, c2W, c2B, msg, E);
    gather_kernel<24><<<nb_nodes, blk, 0, stream>>>(
        x24a, msg, offs, degi, eid, c2R, c2b, x24b, N);

    head_kernel<<<nb_nodes, blk, 0, stream>>>(x24b, oW, ob, (float*)d_out, N);
}